// Round 12
// baseline (39.868 us; speedup 1.0000x reference)
//
#include <hip/hip_runtime.h>
#include <math.h>

// Sampler: iterative Gumbel-softmax relaxed top-k.
// att: [B=256, N=1024, M=4] f32; k=128; out: khot [B,N,M] f32.
// One WAVE per (b,m) column (64 lanes x 16 elems as 8 packed float2).
//
// Structure (R11 spine + R12 forced interleave):
//   S_{t+1} = S_t - 2 r_t P_t + r_t^2 Q_t,  P=sum w^2, Q=sum w^3 (exact).
// Carried spine: 2 fma + rcp. The P/Q DPP chains are textually INTERLEAVED
// with the independent elementwise work (kh-fma, w-update, moment partials)
// using sched_barrier(0) fences — on an in-order wave, later independent
// instructions cannot pass a stalled dependent one, so the interleave must
// be in program order (R11 lesson: chains clumped at body top = stall).
// HEAD iterations use the verified direct-reduce body (tower-cancellation
// guard at t=0..1). w carries exp(2*ag - M0) exactly (verified R4-R11).
// PRNG: JAX threefry2x32 key (0,42), partitionable: counter (0,i),
// bits = out0 ^ out1 (verified R4).

#define N_NODES 1024
#define HEAD 4
#define SB() __builtin_amdgcn_sched_barrier(0)

typedef float f2 __attribute__((ext_vector_type(2)));

__device__ __forceinline__ unsigned rotl32(unsigned x, int r) {
  return (x << r) | (x >> (32 - r));
}

// JAX/Random123 Threefry-2x32, 20 rounds.
__device__ __forceinline__ void threefry2x32(unsigned k0, unsigned k1,
                                             unsigned& x0, unsigned& x1) {
  const unsigned ks0 = k0, ks1 = k1, ks2 = k0 ^ k1 ^ 0x1BD11BDAu;
  x0 += ks0; x1 += ks1;
  x0 += x1; x1 = rotl32(x1, 13); x1 ^= x0;
  x0 += x1; x1 = rotl32(x1, 15); x1 ^= x0;
  x0 += x1; x1 = rotl32(x1, 26); x1 ^= x0;
  x0 += x1; x1 = rotl32(x1, 6);  x1 ^= x0;
  x0 += ks1; x1 += ks2 + 1u;
  x0 += x1; x1 = rotl32(x1, 17); x1 ^= x0;
  x0 += x1; x1 = rotl32(x1, 29); x1 ^= x0;
  x0 += x1; x1 = rotl32(x1, 16); x1 ^= x0;
  x0 += x1; x1 = rotl32(x1, 24); x1 ^= x0;
  x0 += ks2; x1 += ks0 + 2u;
  x0 += x1; x1 = rotl32(x1, 13); x1 ^= x0;
  x0 += x1; x1 = rotl32(x1, 15); x1 ^= x0;
  x0 += x1; x1 = rotl32(x1, 26); x1 ^= x0;
  x0 += x1; x1 = rotl32(x1, 6);  x1 ^= x0;
  x0 += ks0; x1 += ks1 + 3u;
  x0 += x1; x1 = rotl32(x1, 17); x1 ^= x0;
  x0 += x1; x1 = rotl32(x1, 29); x1 ^= x0;
  x0 += x1; x1 = rotl32(x1, 16); x1 ^= x0;
  x0 += x1; x1 = rotl32(x1, 24); x1 ^= x0;
  x0 += ks1; x1 += ks2 + 4u;
  x0 += x1; x1 = rotl32(x1, 13); x1 ^= x0;
  x0 += x1; x1 = rotl32(x1, 15); x1 ^= x0;
  x0 += x1; x1 = rotl32(x1, 26); x1 ^= x0;
  x0 += x1; x1 = rotl32(x1, 6);  x1 ^= x0;
  x0 += ks2; x1 += ks0 + 5u;
}

// --- DPP wave-64 reduction steps (builtin form) ------------------------------
template <int CTRL>
__device__ __forceinline__ float dpp_sum_step(float v) {
  int t = __builtin_amdgcn_update_dpp(0, __float_as_int(v), CTRL, 0xf, 0xf, true);
  return v + __int_as_float(t);
}
template <int CTRL>
__device__ __forceinline__ float dpp_max_step(float v) {
  int iv = __float_as_int(v);
  int t = __builtin_amdgcn_update_dpp(iv, iv, CTRL, 0xf, 0xf, false);
  return fmaxf(v, __int_as_float(t));
}

__device__ __forceinline__ float wave_sum64(float v) {
  v = dpp_sum_step<0x111>(v);
  v = dpp_sum_step<0x112>(v);
  v = dpp_sum_step<0x114>(v);
  v = dpp_sum_step<0x118>(v);
  v = dpp_sum_step<0x142>(v);
  v = dpp_sum_step<0x143>(v);
  return __int_as_float(__builtin_amdgcn_readlane(__float_as_int(v), 63));
}
__device__ __forceinline__ float wave_max64(float v) {
  v = dpp_max_step<0x111>(v);
  v = dpp_max_step<0x112>(v);
  v = dpp_max_step<0x114>(v);
  v = dpp_max_step<0x118>(v);
  v = dpp_max_step<0x142>(v);
  v = dpp_max_step<0x143>(v);
  return __int_as_float(__builtin_amdgcn_readlane(__float_as_int(v), 63));
}

// in-lane pairwise tree: 8 f2 -> scalar
__device__ __forceinline__ float lane_tree8(const f2* a) {
  f2 s0 = a[0] + a[1];
  f2 s1 = a[2] + a[3];
  f2 s2 = a[4] + a[5];
  f2 s3 = a[6] + a[7];
  f2 sA = s0 + s1;
  f2 sB = s2 + s3;
  f2 sC = sA + sB;
  return sC.x + sC.y;
}

__global__ __launch_bounds__(64, 1)
void Sampler_72619307040792_kernel(const float* __restrict__ att,
                                   const int* __restrict__ kp,
                                   float* __restrict__ out) {
  const int col = blockIdx.x;        // 0..1023 = b*4 + m; ONE wave per column
  const int b = col >> 2;
  const int m = col & 3;
  const int lane = threadIdx.x;      // 64 threads = 1 wave
  const int k = *kp;

  const float EPS = __uint_as_float(0x00800000u);  // f32 tiny (normal min)
  const int base = b * 4096 + m;     // + n*4 indexes element n of this column

  float g[16];
  f2 w[8], kh[8];

  // --- init: att + Gumbel noise (threefry partitionable, bits = x0^x1), x2
#pragma unroll
  for (int j = 0; j < 16; ++j) {
    const int n = j * 64 + lane;
    const unsigned idx = (unsigned)(base + n * 4);
    unsigned c0 = 0u, c1 = idx;
    threefry2x32(0u, 42u, c0, c1);
    const unsigned bits = c0 ^ c1;
    const float u = __uint_as_float((bits >> 9) | 0x3F800000u) - 1.0f;
    const float gum = -logf(-logf(u + EPS));
    g[j] = 2.0f * (att[idx] + gum);
  }

  // --- column max M0 (uniform shift; exact softmax equivalence)
  float mx = g[0];
#pragma unroll
  for (int j = 1; j < 16; ++j) mx = fmaxf(mx, g[j]);
  mx = wave_max64(mx);

  // --- w = exp(g - M0) packed; kh = 0
#pragma unroll
  for (int p = 0; p < 8; ++p) {
    f2 t;
    t.x = expf(g[2 * p] - mx);
    t.y = expf(g[2 * p + 1] - mx);
    w[p] = t;
    kh[p] = (f2)(0.0f);
  }

  const f2 one = (f2)(1.0f);
  float S, r;

  // --- HEAD: verified direct-reduce body
  int it = 0;
  const int head = (k < HEAD) ? k : HEAD;
  for (; it < head; ++it) {
    S = wave_sum64(lane_tree8(w));
    r = __builtin_amdgcn_rcpf(S);
    f2 rv;
    rv.x = r;
    rv.y = r;
#pragma unroll
    for (int p = 0; p < 8; ++p)
      kh[p] = __builtin_elementwise_fma(w[p], rv, kh[p]);
#pragma unroll
    for (int p = 0; p < 8; ++p) {
      const f2 u = __builtin_elementwise_fma(-w[p], rv, one);
      const f2 t = w[p] * u;
      w[p] = t * u;
    }
  }

  if (it < k) {
    // transition: direct S for current w + in-lane moment partials tp,tq
    S = wave_sum64(lane_tree8(w));
    r = __builtin_amdgcn_rcpf(S);
    f2 w2[8];
#pragma unroll
    for (int p = 0; p < 8; ++p) w2[p] = w[p] * w[p];
    float tp = lane_tree8(w2);
    f2 qa = (f2)(0.0f), qb = (f2)(0.0f);
#pragma unroll
    for (int p = 0; p < 8; p += 2) {
      qa = __builtin_elementwise_fma(w2[p], w[p], qa);
      qb = __builtin_elementwise_fma(w2[p + 1], w[p + 1], qb);
    }
    f2 qs = qa + qb;
    float tq = qs.x + qs.y;

    // --- STEADY: P/Q DPP chains textually interleaved with independent work
    for (; it < k; ++it) {
      float vP = tp, vQ = tq;
      f2 rv;
      rv.x = r;
      rv.y = r;
      f2 nw[8], nw2[8];

      // [DPP 1] + kh 0..3
      vP = dpp_sum_step<0x111>(vP);
      vQ = dpp_sum_step<0x111>(vQ);
      SB();
      kh[0] = __builtin_elementwise_fma(w[0], rv, kh[0]);
      kh[1] = __builtin_elementwise_fma(w[1], rv, kh[1]);
      kh[2] = __builtin_elementwise_fma(w[2], rv, kh[2]);
      kh[3] = __builtin_elementwise_fma(w[3], rv, kh[3]);
      SB();
      // [DPP 2] + kh 4..7
      vP = dpp_sum_step<0x112>(vP);
      vQ = dpp_sum_step<0x112>(vQ);
      SB();
      kh[4] = __builtin_elementwise_fma(w[4], rv, kh[4]);
      kh[5] = __builtin_elementwise_fma(w[5], rv, kh[5]);
      kh[6] = __builtin_elementwise_fma(w[6], rv, kh[6]);
      kh[7] = __builtin_elementwise_fma(w[7], rv, kh[7]);
      SB();
      // [DPP 3] + w-update 0..3 (+ squares)
      vP = dpp_sum_step<0x114>(vP);
      vQ = dpp_sum_step<0x114>(vQ);
      SB();
#pragma unroll
      for (int p = 0; p < 4; ++p) {
        const f2 u = __builtin_elementwise_fma(-w[p], rv, one);
        const f2 t = w[p] * u;
        nw[p] = t * u;
        nw2[p] = nw[p] * nw[p];
      }
      SB();
      // [DPP 4] + w-update 4..7 (+ squares)
      vP = dpp_sum_step<0x118>(vP);
      vQ = dpp_sum_step<0x118>(vQ);
      SB();
#pragma unroll
      for (int p = 4; p < 8; ++p) {
        const f2 u = __builtin_elementwise_fma(-w[p], rv, one);
        const f2 t = w[p] * u;
        nw[p] = t * u;
        nw2[p] = nw[p] * nw[p];
      }
      SB();
      // [DPP 5] + next tq partials + tp tree level 1
      vP = dpp_sum_step<0x142>(vP);
      vQ = dpp_sum_step<0x142>(vQ);
      SB();
      f2 a0 = (f2)(0.0f), a1 = (f2)(0.0f);
      a0 = __builtin_elementwise_fma(nw2[0], nw[0], a0);
      a1 = __builtin_elementwise_fma(nw2[1], nw[1], a1);
      a0 = __builtin_elementwise_fma(nw2[2], nw[2], a0);
      a1 = __builtin_elementwise_fma(nw2[3], nw[3], a1);
      f2 p0 = nw2[0] + nw2[1];
      f2 p1 = nw2[2] + nw2[3];
      f2 p2 = nw2[4] + nw2[5];
      f2 p3 = nw2[6] + nw2[7];
      SB();
      // [DPP 6] + finish partials
      vP = dpp_sum_step<0x143>(vP);
      vQ = dpp_sum_step<0x143>(vQ);
      SB();
      a0 = __builtin_elementwise_fma(nw2[4], nw[4], a0);
      a1 = __builtin_elementwise_fma(nw2[5], nw[5], a1);
      a0 = __builtin_elementwise_fma(nw2[6], nw[6], a0);
      a1 = __builtin_elementwise_fma(nw2[7], nw[7], a1);
      const f2 pA = p0 + p1;
      const f2 pB = p2 + p3;
      const f2 pC = pA + pB;
      tp = pC.x + pC.y;
      const f2 aS = a0 + a1;
      tq = aS.x + aS.y;
#pragma unroll
      for (int p = 0; p < 8; ++p) w[p] = nw[p];
      SB();
      // spine: P,Q -> S' -> r' (2 fma + rcp; the only carried scalars)
      const float P = __int_as_float(
          __builtin_amdgcn_readlane(__float_as_int(vP), 63));
      const float Q = __int_as_float(
          __builtin_amdgcn_readlane(__float_as_int(vQ), 63));
      const float c1 = fmaf(-2.0f * r, P, S);
      S = fmaf(r * r, Q, c1);
      r = __builtin_amdgcn_rcpf(S);
    }
  }

  // --- store khot
#pragma unroll
  for (int p = 0; p < 8; ++p) {
    out[base + (2 * p * 64 + lane) * 4] = kh[p].x;
    out[base + ((2 * p + 1) * 64 + lane) * 4] = kh[p].y;
  }
}

extern "C" void kernel_launch(void* const* d_in, const int* in_sizes, int n_in,
                              void* d_out, int out_size, void* d_ws, size_t ws_size,
                              hipStream_t stream) {
  const float* att = (const float*)d_in[0];
  const int* kp = (const int*)d_in[1];
  float* out = (float*)d_out;
  const int cols = out_size / N_NODES;  // 1024 columns, one wave each
  Sampler_72619307040792_kernel<<<cols, 64, 0, stream>>>(att, kp, out);
}

// Round 13
// 31.459 us; speedup vs baseline: 1.2673x; 1.2673x over previous
//
#include <hip/hip_runtime.h>
#include <math.h>

// Sampler: iterative Gumbel-softmax relaxed top-k.
// att: [B=256, N=1024, M=4] f32; k=128; out: khot [B,N,M] f32.
// One WAVE per (b,m) column (64 lanes x 16 elems as 8 packed float2).
//
// R13: the R6 algorithm (per-iteration direct reduce — verified best at
// 31.8us) with the elementwise phase HAND-SCHEDULED in inline asm.
// Rationale: every compiler-scheduled variant allocated only 36-44 VGPRs
// (scheduler serializes phases to minimize pressure -> interlock stalls
// dominate, VALUBusy ~30%). The asm block forces 48 distinct VGPRs and a
// schedule where each group of 8 pk-ops is mutually independent.
// Cross-lane reduce: R9's validated fused v_add_f32+DPP sequence.
// w carries exp(2*ag - M0) exactly (verified R4-R12).
// PRNG: JAX threefry2x32 key (0,42), partitionable: counter (0,i),
// bits = out0 ^ out1 (verified R4).

#define N_NODES 1024

typedef float f2 __attribute__((ext_vector_type(2)));

__device__ __forceinline__ unsigned rotl32(unsigned x, int r) {
  return (x << r) | (x >> (32 - r));
}

// JAX/Random123 Threefry-2x32, 20 rounds.
__device__ __forceinline__ void threefry2x32(unsigned k0, unsigned k1,
                                             unsigned& x0, unsigned& x1) {
  const unsigned ks0 = k0, ks1 = k1, ks2 = k0 ^ k1 ^ 0x1BD11BDAu;
  x0 += ks0; x1 += ks1;
  x0 += x1; x1 = rotl32(x1, 13); x1 ^= x0;
  x0 += x1; x1 = rotl32(x1, 15); x1 ^= x0;
  x0 += x1; x1 = rotl32(x1, 26); x1 ^= x0;
  x0 += x1; x1 = rotl32(x1, 6);  x1 ^= x0;
  x0 += ks1; x1 += ks2 + 1u;
  x0 += x1; x1 = rotl32(x1, 17); x1 ^= x0;
  x0 += x1; x1 = rotl32(x1, 29); x1 ^= x0;
  x0 += x1; x1 = rotl32(x1, 16); x1 ^= x0;
  x0 += x1; x1 = rotl32(x1, 24); x1 ^= x0;
  x0 += ks2; x1 += ks0 + 2u;
  x0 += x1; x1 = rotl32(x1, 13); x1 ^= x0;
  x0 += x1; x1 = rotl32(x1, 15); x1 ^= x0;
  x0 += x1; x1 = rotl32(x1, 26); x1 ^= x0;
  x0 += x1; x1 = rotl32(x1, 6);  x1 ^= x0;
  x0 += ks0; x1 += ks1 + 3u;
  x0 += x1; x1 = rotl32(x1, 17); x1 ^= x0;
  x0 += x1; x1 = rotl32(x1, 29); x1 ^= x0;
  x0 += x1; x1 = rotl32(x1, 16); x1 ^= x0;
  x0 += x1; x1 = rotl32(x1, 24); x1 ^= x0;
  x0 += ks1; x1 += ks2 + 4u;
  x0 += x1; x1 = rotl32(x1, 13); x1 ^= x0;
  x0 += x1; x1 = rotl32(x1, 15); x1 ^= x0;
  x0 += x1; x1 = rotl32(x1, 26); x1 ^= x0;
  x0 += x1; x1 = rotl32(x1, 6);  x1 ^= x0;
  x0 += ks2; x1 += ks0 + 5u;
}

// R9-validated fused DPP 64-lane sum; lane63 holds total afterwards.
__device__ __forceinline__ float wave_sum64_fused(float v) {
  asm("s_nop 1\n\t"
      "v_add_f32 %0, %0, %0 row_shr:1 bound_ctrl:0\n\t"
      "s_nop 1\n\t"
      "v_add_f32 %0, %0, %0 row_shr:2 bound_ctrl:0\n\t"
      "s_nop 1\n\t"
      "v_add_f32 %0, %0, %0 row_shr:4 bound_ctrl:0\n\t"
      "s_nop 1\n\t"
      "v_add_f32 %0, %0, %0 row_shr:8 bound_ctrl:0\n\t"
      "s_nop 1\n\t"
      "v_add_f32 %0, %0, %0 row_bcast:15 row_mask:0xa bound_ctrl:0\n\t"
      "s_nop 1\n\t"
      "v_add_f32 %0, %0, %0 row_bcast:31 row_mask:0xc bound_ctrl:0\n\t"
      "s_nop 1"
      : "+v"(v));
  return __int_as_float(__builtin_amdgcn_readlane(__float_as_int(v), 63));
}

// prologue max (builtin form fine here)
template <int CTRL>
__device__ __forceinline__ float dpp_max_step(float v) {
  int iv = __float_as_int(v);
  int t = __builtin_amdgcn_update_dpp(iv, iv, CTRL, 0xf, 0xf, false);
  return fmaxf(v, __int_as_float(t));
}
__device__ __forceinline__ float wave_max64(float v) {
  v = dpp_max_step<0x111>(v);
  v = dpp_max_step<0x112>(v);
  v = dpp_max_step<0x114>(v);
  v = dpp_max_step<0x118>(v);
  v = dpp_max_step<0x142>(v);
  v = dpp_max_step<0x143>(v);
  return __int_as_float(__builtin_amdgcn_readlane(__float_as_int(v), 63));
}

// in-lane pairwise tree: 8 f2 -> scalar
__device__ __forceinline__ float lane_tree8(const f2* a) {
  f2 s0 = a[0] + a[1];
  f2 s1 = a[2] + a[3];
  f2 s2 = a[4] + a[5];
  f2 s3 = a[6] + a[7];
  f2 sA = s0 + s1;
  f2 sB = s2 + s3;
  f2 sC = sA + sB;
  return sC.x + sC.y;
}

__global__ __launch_bounds__(64, 1)
void Sampler_72619307040792_kernel(const float* __restrict__ att,
                                   const int* __restrict__ kp,
                                   float* __restrict__ out) {
  const int col = blockIdx.x;        // 0..1023 = b*4 + m; ONE wave per column
  const int b = col >> 2;
  const int m = col & 3;
  const int lane = threadIdx.x;      // 64 threads = 1 wave
  const int k = *kp;

  const float EPS = __uint_as_float(0x00800000u);  // f32 tiny (normal min)
  const int base = b * 4096 + m;     // + n*4 indexes element n of this column

  float g[16];
  f2 w[8], kh[8];

  // --- init: att + Gumbel noise (threefry partitionable, bits = x0^x1), x2
#pragma unroll
  for (int j = 0; j < 16; ++j) {
    const int n = j * 64 + lane;
    const unsigned idx = (unsigned)(base + n * 4);
    unsigned c0 = 0u, c1 = idx;
    threefry2x32(0u, 42u, c0, c1);
    const unsigned bits = c0 ^ c1;
    const float u = __uint_as_float((bits >> 9) | 0x3F800000u) - 1.0f;
    const float gum = -logf(-logf(u + EPS));
    g[j] = 2.0f * (att[idx] + gum);
  }

  // --- column max M0 (uniform shift; exact softmax equivalence)
  float mx = g[0];
#pragma unroll
  for (int j = 1; j < 16; ++j) mx = fmaxf(mx, g[j]);
  mx = wave_max64(mx);

  // --- w = exp(g - M0) packed; kh = 0
#pragma unroll
  for (int p = 0; p < 8; ++p) {
    f2 t;
    t.x = expf(g[2 * p] - mx);
    t.y = expf(g[2 * p + 1] - mx);
    w[p] = t;
    kh[p] = (f2)(0.0f);
  }

  if (k <= 0) {
#pragma unroll
    for (int p = 0; p < 8; ++p) {
      out[base + (2 * p * 64 + lane) * 4] = 0.0f;
      out[base + ((2 * p + 1) * 64 + lane) * 4] = 0.0f;
    }
    return;
  }

  const f2 one = {1.0f, 1.0f};

  // initial S, r (for iteration 1)
  float S = wave_sum64_fused(lane_tree8(w));
  float r = __builtin_amdgcn_rcpf(S);
  f2 rv, nr;
  rv.x = r;  rv.y = r;
  nr.x = -r; nr.y = -r;

  f2 t0, t1, t2, t3, t4, t5, t6, t7;

  for (int it = 0; it < k; ++it) {
    // --- hand-scheduled elementwise phase: 48 forced-distinct VGPR pairs.
    // group 1: kh += w*r   (8 independent pk fma)
    // group 2: t = 1 - w*r (8 independent pk fma)
    // group 3: w = w*t     (8 independent pk mul)
    // group 4: w = w*t     (8 independent pk mul)
    asm("v_pk_fma_f32 %[k0], %[a0], %[rv], %[k0]\n\t"
        "v_pk_fma_f32 %[k1], %[a1], %[rv], %[k1]\n\t"
        "v_pk_fma_f32 %[k2], %[a2], %[rv], %[k2]\n\t"
        "v_pk_fma_f32 %[k3], %[a3], %[rv], %[k3]\n\t"
        "v_pk_fma_f32 %[k4], %[a4], %[rv], %[k4]\n\t"
        "v_pk_fma_f32 %[k5], %[a5], %[rv], %[k5]\n\t"
        "v_pk_fma_f32 %[k6], %[a6], %[rv], %[k6]\n\t"
        "v_pk_fma_f32 %[k7], %[a7], %[rv], %[k7]\n\t"
        "v_pk_fma_f32 %[t0], %[a0], %[nr], %[on]\n\t"
        "v_pk_fma_f32 %[t1], %[a1], %[nr], %[on]\n\t"
        "v_pk_fma_f32 %[t2], %[a2], %[nr], %[on]\n\t"
        "v_pk_fma_f32 %[t3], %[a3], %[nr], %[on]\n\t"
        "v_pk_fma_f32 %[t4], %[a4], %[nr], %[on]\n\t"
        "v_pk_fma_f32 %[t5], %[a5], %[nr], %[on]\n\t"
        "v_pk_fma_f32 %[t6], %[a6], %[nr], %[on]\n\t"
        "v_pk_fma_f32 %[t7], %[a7], %[nr], %[on]\n\t"
        "v_pk_mul_f32 %[a0], %[a0], %[t0]\n\t"
        "v_pk_mul_f32 %[a1], %[a1], %[t1]\n\t"
        "v_pk_mul_f32 %[a2], %[a2], %[t2]\n\t"
        "v_pk_mul_f32 %[a3], %[a3], %[t3]\n\t"
        "v_pk_mul_f32 %[a4], %[a4], %[t4]\n\t"
        "v_pk_mul_f32 %[a5], %[a5], %[t5]\n\t"
        "v_pk_mul_f32 %[a6], %[a6], %[t6]\n\t"
        "v_pk_mul_f32 %[a7], %[a7], %[t7]\n\t"
        "v_pk_mul_f32 %[a0], %[a0], %[t0]\n\t"
        "v_pk_mul_f32 %[a1], %[a1], %[t1]\n\t"
        "v_pk_mul_f32 %[a2], %[a2], %[t2]\n\t"
        "v_pk_mul_f32 %[a3], %[a3], %[t3]\n\t"
        "v_pk_mul_f32 %[a4], %[a4], %[t4]\n\t"
        "v_pk_mul_f32 %[a5], %[a5], %[t5]\n\t"
        "v_pk_mul_f32 %[a6], %[a6], %[t6]\n\t"
        "v_pk_mul_f32 %[a7], %[a7], %[t7]"
        : [a0] "+v"(w[0]), [a1] "+v"(w[1]), [a2] "+v"(w[2]), [a3] "+v"(w[3]),
          [a4] "+v"(w[4]), [a5] "+v"(w[5]), [a6] "+v"(w[6]), [a7] "+v"(w[7]),
          [k0] "+v"(kh[0]), [k1] "+v"(kh[1]), [k2] "+v"(kh[2]),
          [k3] "+v"(kh[3]), [k4] "+v"(kh[4]), [k5] "+v"(kh[5]),
          [k6] "+v"(kh[6]), [k7] "+v"(kh[7]),
          [t0] "=&v"(t0), [t1] "=&v"(t1), [t2] "=&v"(t2), [t3] "=&v"(t3),
          [t4] "=&v"(t4), [t5] "=&v"(t5), [t6] "=&v"(t6), [t7] "=&v"(t7)
        : [rv] "v"(rv), [nr] "v"(nr), [on] "v"(one));

    // --- next S, r (last pass computes an unused r; harmless)
    S = wave_sum64_fused(lane_tree8(w));
    r = __builtin_amdgcn_rcpf(S);
    rv.x = r;  rv.y = r;
    nr.x = -r; nr.y = -r;
  }

  // --- store khot
#pragma unroll
  for (int p = 0; p < 8; ++p) {
    out[base + (2 * p * 64 + lane) * 4] = kh[p].x;
    out[base + ((2 * p + 1) * 64 + lane) * 4] = kh[p].y;
  }
}

extern "C" void kernel_launch(void* const* d_in, const int* in_sizes, int n_in,
                              void* d_out, int out_size, void* d_ws, size_t ws_size,
                              hipStream_t stream) {
  const float* att = (const float*)d_in[0];
  const int* kp = (const int*)d_in[1];
  float* out = (float*)d_out;
  const int cols = out_size / N_NODES;  // 1024 columns, one wave each
  Sampler_72619307040792_kernel<<<cols, 64, 0, stream>>>(att, kp, out);
}